// Round 8
// baseline (1315143.457 us; speedup 1.0000x reference)
//
#include <hip/hip_runtime.h>
#include <math.h>

#define TPB     128
#define NBATCH  64
#define SPB     16
#define NBLK    (NBATCH*SPB)       // 1024 blocks, 4/CU — co-residency guaranteed
#define SROWS   16
#define MM      256
#define AN      257
#define NITER   300
#define NIT1    (NITER+1)
#define SARR    (NBATCH*NIT1)      // ints per counter/flag array
#define RS      264
#define CO(k)   ((k) + ((k) >> 5))

// ---- contraction-proof IEEE fp32 ops (trajectory must match ref's separate
// mul/add/sub elementwise arithmetic; inline asm is opaque to FMA formation).
__device__ __forceinline__ float mulf(float a, float b) {
  float d; asm("v_mul_f32 %0, %1, %2" : "=v"(d) : "v"(a), "v"(b)); return d;
}
__device__ __forceinline__ float addf(float a, float b) {
  float d; asm("v_add_f32 %0, %1, %2" : "=v"(d) : "v"(a), "v"(b)); return d;
}
__device__ __forceinline__ float subf(float a, float b) {
  float d; asm("v_sub_f32 %0, %1, %2" : "=v"(d) : "v"(a), "v"(b)); return d;
}
// dot-product accumulate: single-rounded FMA (BLAS sdot / XLA reduce use FMA)
__device__ __forceinline__ float fmacf(float acc, float x, float y) {
  asm("v_fmac_f32 %0, %1, %2" : "+v"(acc) : "v"(x), "v"(y)); return acc;
}

__global__ void init_ws_kernel(int* __restrict__ z, int n) {
  int i = blockIdx.x * blockDim.x + threadIdx.x;
  if (i < n) z[i] = 0;
}

__device__ __forceinline__ void waitEq(int* p, int target) {
  int tries = 0;
  while (__hip_atomic_load(p, __ATOMIC_ACQUIRE, __HIP_MEMORY_SCOPE_AGENT) < target) {
    __builtin_amdgcn_s_sleep(2);
    if (++tries > (1 << 25)) break;   // hang-safety valve
  }
  __threadfence();
}

// Bit-faithful BLAS-sdot-style dot: 32 slots, slot s sums elements g≡s (mod 32)
// in ascending g via FMA chains of 2048; combine = ((v0+v1)+(v2+v3)) lanewise,
// fold hi/lo halves, then ((d0+d1)+(d2+d3)). Lanes 0..31; result on all lanes.
__device__ float dot32(const float* __restrict__ X, const float* __restrict__ Y,
                       int lane) {
  float acc = 0.0f;
  const float* xp = X + lane;
  const float* yp = Y + lane;
  #pragma unroll 8
  for (int t = 0; t < 2048; ++t) acc = fmacf(acc, xp[t * 32], yp[t * 32]);
  float d[32];
  #pragma unroll
  for (int o = 0; o < 32; ++o) d[o] = __shfl(acc, o, 64);
  float C[8];
  #pragma unroll
  for (int l = 0; l < 8; ++l)
    C[l] = addf(addf(d[l], d[8 + l]), addf(d[16 + l], d[24 + l]));
  float D[4];
  #pragma unroll
  for (int l = 0; l < 4; ++l) D[l] = addf(C[l], C[l + 4]);
  return addf(addf(D[0], D[1]), addf(D[2], D[3]));
}

__launch_bounds__(TPB, 2)
__global__ void cg_kernel(const float* __restrict__ alpha,
                          const float* __restrict__ frhs,
                          float* __restrict__ out,
                          int* __restrict__ Z,      // counters/flags region
                          float* __restrict__ av,   // alpha[b][it]
                          float* __restrict__ bv,   // beta[b][it] (debug)
                          float* __restrict__ halo,
                          float* __restrict__ pbuf,
                          float* __restrict__ apbuf,
                          float* __restrict__ rbuf)
{
  __shared__ float sP[(SROWS + 2) * RS];

  int* cntP  = Z + 0 * SARR;   // strip phase-C (p ready) per [b][it]
  int* cntA  = Z + 1 * SARR;   // strip phase-A (Ap ready)
  int* cntB  = Z + 2 * SARR;   // strip phase-B (r ready)
  int* flagA = Z + 3 * SARR;   // reducer: alpha ready
  int* flagB = Z + 4 * SARR;   // reducer: beta ready

  const int tid  = threadIdx.x;
  const int bx   = blockIdx.x;
  const int b    = bx >> 4;
  const int s    = bx & 15;
  const int js   = s * SROWS;
  const int jloc = tid >> 3;
  const int k0   = (tid & 7) << 5;
  const int jg   = js + jloc;
  const int rowb = (jloc + 1) * RS;
  const size_t gbase = (size_t)b * (MM * MM) + (size_t)jg * MM + k0;

  // ---- coefficients once, reference fp32 rounding order
  float kl[32], kr[32], kb[32], kt[32], dg[32];
  {
    const float* r0 = alpha + (size_t)b * (AN * AN) + (size_t)jg * AN + k0;
    const float* r1 = r0 + AN;
    float a0[33], a1[33];
    #pragma unroll
    for (int i = 0; i < 33; ++i) { a0[i] = r0[i]; a1[i] = r1[i]; }
    #pragma unroll
    for (int i = 0; i < 32; ++i) {
      const int kg = k0 + i;
      float vkl = expf(0.5f * (a0[i] + a0[i + 1]));
      float vkr = (jg < MM - 1) ? expf(0.5f * (a1[i] + a1[i + 1])) : 0.0f;
      float vkb = (kg > 0)      ? expf(0.5f * (a0[i] + a1[i]))     : 0.0f;
      float vkt = (kg < MM - 1) ? expf(0.5f * (a0[i + 1] + a1[i + 1])) : 0.0f;
      float d = ((vkl + vkr) + vkb) + vkt;
      if (jg == 0) d += vkl;
      kl[i] = vkl; kr[i] = vkr; kb[i] = vkb; kt[i] = vkt; dg[i] = d;
    }
  }

  float uu[32], rr[32], pp[32], Ap[32];
  {
    const float* fB = frhs + (size_t)jg * MM + k0;
    #pragma unroll
    for (int i = 0; i < 32; ++i) {
      float v = fB[i];
      uu[i] = 0.0f; rr[i] = v; pp[i] = v;
      sP[rowb + CO(k0 + i)] = v;
      pbuf[gbase + i] = v;
      rbuf[gbase + i] = v;
    }
  }
  float* myhalo = halo + (size_t)bx * 512;
  if (jloc == 0) {
    #pragma unroll
    for (int i = 0; i < 32; ++i) myhalo[k0 + i] = pp[i];
  }
  if (jloc == SROWS - 1) {
    #pragma unroll
    for (int i = 0; i < 32; ++i) myhalo[256 + k0 + i] = pp[i];
  }
  __syncthreads();
  if (tid == 0) {
    __threadfence();
    __hip_atomic_fetch_add(&cntP[b * NIT1 + 0], 1, __ATOMIC_ACQ_REL,
                           __HIP_MEMORY_SCOPE_AGENT);
  }

  float gamma_red = 0.0f;   // live only in s==0, tid<32

  for (int it = 1; it <= NITER; ++it) {
    // ---- phase A: wait p/halos ready, stencil, publish Ap
    if (tid == 0) waitEq(&cntP[b * NIT1 + it - 1], SPB);
    __syncthreads();
    if (jloc == 0) {
      if (s > 0) {
        float* nh = halo + (size_t)(bx - 1) * 512 + 256;
        #pragma unroll
        for (int i = 0; i < 32; ++i) sP[CO(k0 + i)] = nh[k0 + i];
      } else {
        #pragma unroll
        for (int i = 0; i < 32; ++i) sP[CO(k0 + i)] = 0.0f;
      }
    }
    if (jloc == SROWS - 1) {
      if (s < SPB - 1) {
        float* nh = halo + (size_t)(bx + 1) * 512;
        #pragma unroll
        for (int i = 0; i < 32; ++i) sP[(SROWS + 1) * RS + CO(k0 + i)] = nh[k0 + i];
      } else {
        #pragma unroll
        for (int i = 0; i < 32; ++i) sP[(SROWS + 1) * RS + CO(k0 + i)] = 0.0f;
      }
    }
    __syncthreads();

    #pragma unroll
    for (int i = 0; i < 32; ++i) {
      const int kg = k0 + i;
      float pc = pp[i];
      float pd = sP[rowb - RS + CO(kg)];
      float pu = sP[rowb + RS + CO(kg)];
      float pl = (i > 0) ? pp[i - 1]
                         : ((k0 > 0) ? sP[rowb + CO(k0 - 1)] : 0.0f);
      float pr = (i < 31) ? pp[i + 1]
                          : ((kg < MM - 1) ? sP[rowb + CO(k0 + 32)] : 0.0f);
      float t = mulf(dg[i], pc);
      t = subf(t, mulf(kl[i], pd));
      t = subf(t, mulf(kr[i], pu));
      t = subf(t, mulf(kb[i], pl));
      t = subf(t, mulf(kt[i], pr));
      float ap = mulf(65536.0f, t);
      Ap[i] = ap;
      apbuf[gbase + i] = ap;
    }
    __syncthreads();
    if (tid == 0) {
      __threadfence();
      __hip_atomic_fetch_add(&cntA[b * NIT1 + it], 1, __ATOMIC_ACQ_REL,
                             __HIP_MEMORY_SCOPE_AGENT);
    }

    // ---- reducer: alpha = gamma / (p.Ap)
    if (s == 0 && tid < 32) {
      waitEq(&cntA[b * NIT1 + it], SPB);
      const float* Pb  = pbuf  + (size_t)b * (MM * MM);
      const float* APb = apbuf + (size_t)b * (MM * MM);
      const float* Rb  = rbuf  + (size_t)b * (MM * MM);
      if (it == 1) gamma_red = dot32(Rb, Rb, tid);   // gamma0 = r0.r0
      float pap = dot32(Pb, APb, tid);
      if (tid == 0) {
        av[b * NIT1 + it] = gamma_red / pap;         // fp32 divide
        __threadfence();
        __hip_atomic_store(&flagA[b * NIT1 + it], 1, __ATOMIC_RELEASE,
                           __HIP_MEMORY_SCOPE_AGENT);
      }
    }

    // ---- phase B: x += a p ; r -= a Ap ; publish r
    if (tid == 0) waitEq(&flagA[b * NIT1 + it], 1);
    __syncthreads();
    float alf = av[b * NIT1 + it];
    #pragma unroll
    for (int i = 0; i < 32; ++i) {
      uu[i] = addf(uu[i], mulf(alf, pp[i]));
      rr[i] = subf(rr[i], mulf(alf, Ap[i]));
      rbuf[gbase + i] = rr[i];
    }
    __syncthreads();
    if (tid == 0) {
      __threadfence();
      __hip_atomic_fetch_add(&cntB[b * NIT1 + it], 1, __ATOMIC_ACQ_REL,
                             __HIP_MEMORY_SCOPE_AGENT);
    }

    // ---- reducer: beta = gamma'/gamma
    if (s == 0 && tid < 32) {
      waitEq(&cntB[b * NIT1 + it], SPB);
      const float* Rb = rbuf + (size_t)b * (MM * MM);
      float g2 = dot32(Rb, Rb, tid);
      float bet = g2 / gamma_red;                    // fp32 divide
      gamma_red = g2;
      if (tid == 0) {
        bv[b * NIT1 + it] = bet;
        __threadfence();
        __hip_atomic_store(&flagB[b * NIT1 + it], 1, __ATOMIC_RELEASE,
                           __HIP_MEMORY_SCOPE_AGENT);
      }
    }

    // ---- phase C: p = r + b p ; publish p + halos
    if (tid == 0) waitEq(&flagB[b * NIT1 + it], 1);
    __syncthreads();
    float bet = bv[b * NIT1 + it];
    #pragma unroll
    for (int i = 0; i < 32; ++i) {
      float pn = addf(rr[i], mulf(bet, pp[i]));
      pp[i] = pn;
      sP[rowb + CO(k0 + i)] = pn;
      pbuf[gbase + i] = pn;
    }
    if (jloc == 0) {
      #pragma unroll
      for (int i = 0; i < 32; ++i) myhalo[k0 + i] = pp[i];
    }
    if (jloc == SROWS - 1) {
      #pragma unroll
      for (int i = 0; i < 32; ++i) myhalo[256 + k0 + i] = pp[i];
    }
    __syncthreads();
    if (tid == 0) {
      __threadfence();
      __hip_atomic_fetch_add(&cntP[b * NIT1 + it], 1, __ATOMIC_ACQ_REL,
                             __HIP_MEMORY_SCOPE_AGENT);
    }
  }

  float* oB = out + gbase;
  #pragma unroll
  for (int i = 0; i < 32; ++i) oB[i] = uu[i];
}

extern "C" void kernel_launch(void* const* d_in, const int* in_sizes, int n_in,
                              void* d_out, int out_size, void* d_ws, size_t ws_size,
                              hipStream_t stream) {
  const float* alpha = (const float*)d_in[0];   // (64, 257, 257) fp32
  const float* frhs  = (const float*)d_in[1];   // (256, 256) fp32
  float* out = (float*)d_out;                   // (64, 256, 256) fp32

  char* ws = (char*)d_ws;
  int*   Z    = (int*)ws;                               // 5 int arrays [64][301]
  float* av   = (float*)(ws + (size_t)5 * SARR * 4);
  float* bv   = (float*)(ws + (size_t)6 * SARR * 4);
  size_t ZR   = ((size_t)7 * SARR * 4 + 4095) & ~(size_t)4095;
  float* halo  = (float*)(ws + ZR);                     // 2 MB
  float* pbuf  = (float*)(ws + ZR + (size_t)NBLK * 512 * 4);
  float* apbuf = pbuf  + (size_t)NBATCH * MM * MM;      // 16 MB each
  float* rbuf  = apbuf + (size_t)NBATCH * MM * MM;

  int nz = 5 * SARR;   // zero only counters/flags (av/bv are written before read)
  hipLaunchKernelGGL(init_ws_kernel, dim3((nz + 255) / 256), dim3(256), 0, stream,
                     Z, nz);
  hipLaunchKernelGGL(cg_kernel, dim3(NBLK), dim3(TPB), 0, stream,
                     alpha, frhs, out, Z, av, bv, halo, pbuf, apbuf, rbuf);
}

// Round 9
// 63776.410 us; speedup vs baseline: 20.6212x; 20.6212x over previous
//
#include <hip/hip_runtime.h>
#include <math.h>

#define TPB     128
#define NBATCH  64
#define SPB     16
#define NBLK    (NBATCH*SPB)       // 1024 blocks, 4/CU — co-residency guaranteed
#define SROWS   16
#define MM      256
#define AN      257
#define NITER   300
#define NIT1    (NITER+1)
#define SARR    (NBATCH*NIT1)      // ints per counter/flag array
#define RS      264
#define CO(k)   ((k) + ((k) >> 5))

// ---- contraction-proof IEEE fp32 ops (trajectory bit-identical to R8).
__device__ __forceinline__ float mulf(float a, float b) {
  float d; asm("v_mul_f32 %0, %1, %2" : "=v"(d) : "v"(a), "v"(b)); return d;
}
__device__ __forceinline__ float addf(float a, float b) {
  float d; asm("v_add_f32 %0, %1, %2" : "=v"(d) : "v"(a), "v"(b)); return d;
}
__device__ __forceinline__ float subf(float a, float b) {
  float d; asm("v_sub_f32 %0, %1, %2" : "=v"(d) : "v"(a), "v"(b)); return d;
}
__device__ __forceinline__ float fmacf(float acc, float x, float y) {
  asm("v_fmac_f32 %0, %1, %2" : "+v"(acc) : "v"(x), "v"(y)); return acc;
}

// ---- cache-bypassing coherent transport (NO bulk inv/wb anywhere):
// relaxed agent-scope atomics compile to global_load/store sc0 sc1 (per-access
// coherent at the LLC). Producer ordering = s_waitcnt vmcnt(0) before bump.
#define ALD_F(p)    __hip_atomic_load((p),  __ATOMIC_RELAXED, __HIP_MEMORY_SCOPE_AGENT)
#define AST_F(p,v)  __hip_atomic_store((p), (v), __ATOMIC_RELAXED, __HIP_MEMORY_SCOPE_AGENT)
#define ALD_I(p)    __hip_atomic_load((p),  __ATOMIC_RELAXED, __HIP_MEMORY_SCOPE_AGENT)

__device__ __forceinline__ void drain_vm() {
  asm volatile("s_waitcnt vmcnt(0) lgkmcnt(0)" ::: "memory");
}

__global__ void init_ws_kernel(int* __restrict__ z, int n) {
  int i = blockIdx.x * blockDim.x + threadIdx.x;
  if (i < n) z[i] = 0;
}

// relaxed spin — no acquire, no cache maintenance; data moves via sc0sc1 atomics
__device__ __forceinline__ void waitEq(int* p, int target) {
  int tries = 0;
  while (ALD_I(p) < target) {
    __builtin_amdgcn_s_sleep(4);
    if (++tries > (1 << 22)) break;   // hang-safety valve (never expected)
  }
}

// Bit-faithful copy of R8's dot: 32 slots, slot l sums g≡l (mod 32) ascending
// via one FMA chain of 2048 (single-rounded fmac); combine tree identical.
// Transport: double-buffered 32-element groups of relaxed-atomic loads
// (~64 loads in flight) to hide LLC latency. Result on all lanes 0..31.
__device__ float dot32(float* X, float* Y, int lane) {
  float* xp = X + lane;
  float* yp = Y + lane;
  float xa[32], ya[32], xb[32], yb[32];
  float acc = 0.0f;
  #pragma unroll
  for (int i = 0; i < 32; ++i) { xa[i] = ALD_F(xp + i * 32); ya[i] = ALD_F(yp + i * 32); }
  #pragma unroll 1
  for (int g = 0; g < 64; g += 2) {
    #pragma unroll
    for (int i = 0; i < 32; ++i) {             // prefetch group g+1
      xb[i] = ALD_F(xp + ((g + 1) * 32 + i) * 32);
      yb[i] = ALD_F(yp + ((g + 1) * 32 + i) * 32);
    }
    #pragma unroll
    for (int i = 0; i < 32; ++i) acc = fmacf(acc, xa[i], ya[i]);   // consume g
    if (g + 2 < 64) {
      #pragma unroll
      for (int i = 0; i < 32; ++i) {           // prefetch group g+2
        xa[i] = ALD_F(xp + ((g + 2) * 32 + i) * 32);
        ya[i] = ALD_F(yp + ((g + 2) * 32 + i) * 32);
      }
    }
    #pragma unroll
    for (int i = 0; i < 32; ++i) acc = fmacf(acc, xb[i], yb[i]);   // consume g+1
  }
  float d[32];
  #pragma unroll
  for (int o = 0; o < 32; ++o) d[o] = __shfl(acc, o, 64);
  float C[8];
  #pragma unroll
  for (int l = 0; l < 8; ++l)
    C[l] = addf(addf(d[l], d[8 + l]), addf(d[16 + l], d[24 + l]));
  float D[4];
  #pragma unroll
  for (int l = 0; l < 4; ++l) D[l] = addf(C[l], C[l + 4]);
  return addf(addf(D[0], D[1]), addf(D[2], D[3]));
}

__launch_bounds__(TPB, 2)
__global__ void cg_kernel(const float* __restrict__ alpha,
                          const float* __restrict__ frhs,
                          float* __restrict__ out,
                          int* __restrict__ Z,
                          float* __restrict__ av,
                          float* __restrict__ bv,
                          float* __restrict__ halo,
                          float* __restrict__ pbuf,
                          float* __restrict__ apbuf,
                          float* __restrict__ rbuf)
{
  __shared__ float sP[(SROWS + 2) * RS];

  int* cntP  = Z + 0 * SARR;
  int* cntA  = Z + 1 * SARR;
  int* cntB  = Z + 2 * SARR;
  int* flagA = Z + 3 * SARR;
  int* flagB = Z + 4 * SARR;

  const int tid  = threadIdx.x;
  const int bx   = blockIdx.x;
  const int b    = bx >> 4;
  const int s    = bx & 15;
  const int js   = s * SROWS;
  const int jloc = tid >> 3;
  const int k0   = (tid & 7) << 5;
  const int jg   = js + jloc;
  const int rowb = (jloc + 1) * RS;
  const size_t gbase = (size_t)b * (MM * MM) + (size_t)jg * MM + k0;

  // ---- coefficients once, reference fp32 rounding order (bit-identical to R8)
  float kl[32], kr[32], kb[32], kt[32], dg[32];
  {
    const float* r0 = alpha + (size_t)b * (AN * AN) + (size_t)jg * AN + k0;
    const float* r1 = r0 + AN;
    float a0[33], a1[33];
    #pragma unroll
    for (int i = 0; i < 33; ++i) { a0[i] = r0[i]; a1[i] = r1[i]; }
    #pragma unroll
    for (int i = 0; i < 32; ++i) {
      const int kg = k0 + i;
      float vkl = expf(0.5f * (a0[i] + a0[i + 1]));
      float vkr = (jg < MM - 1) ? expf(0.5f * (a1[i] + a1[i + 1])) : 0.0f;
      float vkb = (kg > 0)      ? expf(0.5f * (a0[i] + a1[i]))     : 0.0f;
      float vkt = (kg < MM - 1) ? expf(0.5f * (a0[i + 1] + a1[i + 1])) : 0.0f;
      float d = ((vkl + vkr) + vkb) + vkt;
      if (jg == 0) d += vkl;
      kl[i] = vkl; kr[i] = vkr; kb[i] = vkb; kt[i] = vkt; dg[i] = d;
    }
  }

  float uu[32], rr[32], pp[32], Ap[32];
  {
    const float* fB = frhs + (size_t)jg * MM + k0;
    #pragma unroll
    for (int i = 0; i < 32; ++i) {
      float v = fB[i];
      uu[i] = 0.0f; rr[i] = v; pp[i] = v;
      sP[rowb + CO(k0 + i)] = v;
      AST_F(&pbuf[gbase + i], v);
      AST_F(&rbuf[gbase + i], v);
    }
  }
  float* myhalo = halo + (size_t)bx * 512;
  if (jloc == 0) {
    #pragma unroll
    for (int i = 0; i < 32; ++i) AST_F(&myhalo[k0 + i], pp[i]);
  }
  if (jloc == SROWS - 1) {
    #pragma unroll
    for (int i = 0; i < 32; ++i) AST_F(&myhalo[256 + k0 + i], pp[i]);
  }
  drain_vm();
  __syncthreads();
  if (tid == 0)
    __hip_atomic_fetch_add(&cntP[b * NIT1 + 0], 1, __ATOMIC_RELAXED,
                           __HIP_MEMORY_SCOPE_AGENT);

  float gamma_red = 0.0f;   // live only in s==0, tid<32

  for (int it = 1; it <= NITER; ++it) {
    // ---- phase A: wait p ready, stencil, publish Ap
    if (tid == 0) waitEq(&cntP[b * NIT1 + it - 1], SPB);
    __syncthreads();
    if (jloc == 0) {
      if (s > 0) {
        float* nh = halo + (size_t)(bx - 1) * 512 + 256;
        #pragma unroll
        for (int i = 0; i < 32; ++i) sP[CO(k0 + i)] = ALD_F(&nh[k0 + i]);
      } else {
        #pragma unroll
        for (int i = 0; i < 32; ++i) sP[CO(k0 + i)] = 0.0f;
      }
    }
    if (jloc == SROWS - 1) {
      if (s < SPB - 1) {
        float* nh = halo + (size_t)(bx + 1) * 512;
        #pragma unroll
        for (int i = 0; i < 32; ++i) sP[(SROWS + 1) * RS + CO(k0 + i)] = ALD_F(&nh[k0 + i]);
      } else {
        #pragma unroll
        for (int i = 0; i < 32; ++i) sP[(SROWS + 1) * RS + CO(k0 + i)] = 0.0f;
      }
    }
    __syncthreads();

    #pragma unroll
    for (int i = 0; i < 32; ++i) {
      const int kg = k0 + i;
      float pc = pp[i];
      float pd = sP[rowb - RS + CO(kg)];
      float pu = sP[rowb + RS + CO(kg)];
      float pl = (i > 0) ? pp[i - 1]
                         : ((k0 > 0) ? sP[rowb + CO(k0 - 1)] : 0.0f);
      float pr = (i < 31) ? pp[i + 1]
                          : ((kg < MM - 1) ? sP[rowb + CO(k0 + 32)] : 0.0f);
      float t = mulf(dg[i], pc);
      t = subf(t, mulf(kl[i], pd));
      t = subf(t, mulf(kr[i], pu));
      t = subf(t, mulf(kb[i], pl));
      t = subf(t, mulf(kt[i], pr));
      float ap = mulf(65536.0f, t);
      Ap[i] = ap;
      AST_F(&apbuf[gbase + i], ap);
    }
    drain_vm();
    __syncthreads();
    if (tid == 0)
      __hip_atomic_fetch_add(&cntA[b * NIT1 + it], 1, __ATOMIC_RELAXED,
                             __HIP_MEMORY_SCOPE_AGENT);

    // ---- reducer: alpha = gamma / (p.Ap)
    if (s == 0 && tid < 32) {
      waitEq(&cntA[b * NIT1 + it], SPB);
      float* Pb  = pbuf  + (size_t)b * (MM * MM);
      float* APb = apbuf + (size_t)b * (MM * MM);
      float* Rb  = rbuf  + (size_t)b * (MM * MM);
      if (it == 1) gamma_red = dot32(Rb, Rb, tid);
      float pap = dot32(Pb, APb, tid);
      if (tid == 0) {
        AST_F(&av[b * NIT1 + it], gamma_red / pap);
        drain_vm();   // av visible before flag
        __hip_atomic_store(&flagA[b * NIT1 + it], 1, __ATOMIC_RELAXED,
                           __HIP_MEMORY_SCOPE_AGENT);
      }
    }

    // ---- phase B: x += a p ; r -= a Ap ; publish r
    if (tid == 0) waitEq(&flagA[b * NIT1 + it], 1);
    __syncthreads();
    float alf = ALD_F(&av[b * NIT1 + it]);
    #pragma unroll
    for (int i = 0; i < 32; ++i) {
      uu[i] = addf(uu[i], mulf(alf, pp[i]));
      rr[i] = subf(rr[i], mulf(alf, Ap[i]));
      AST_F(&rbuf[gbase + i], rr[i]);
    }
    drain_vm();
    __syncthreads();
    if (tid == 0)
      __hip_atomic_fetch_add(&cntB[b * NIT1 + it], 1, __ATOMIC_RELAXED,
                             __HIP_MEMORY_SCOPE_AGENT);

    // ---- reducer: beta = gamma'/gamma
    if (s == 0 && tid < 32) {
      waitEq(&cntB[b * NIT1 + it], SPB);
      float* Rb = rbuf + (size_t)b * (MM * MM);
      float g2 = dot32(Rb, Rb, tid);
      float bet = g2 / gamma_red;
      gamma_red = g2;
      if (tid == 0) {
        AST_F(&bv[b * NIT1 + it], bet);
        drain_vm();   // bv visible before flag
        __hip_atomic_store(&flagB[b * NIT1 + it], 1, __ATOMIC_RELAXED,
                           __HIP_MEMORY_SCOPE_AGENT);
      }
    }

    // ---- phase C: p = r + b p ; publish p + halos
    if (tid == 0) waitEq(&flagB[b * NIT1 + it], 1);
    __syncthreads();
    float bet = ALD_F(&bv[b * NIT1 + it]);
    #pragma unroll
    for (int i = 0; i < 32; ++i) {
      float pn = addf(rr[i], mulf(bet, pp[i]));
      pp[i] = pn;
      sP[rowb + CO(k0 + i)] = pn;
      AST_F(&pbuf[gbase + i], pn);
    }
    if (jloc == 0) {
      #pragma unroll
      for (int i = 0; i < 32; ++i) AST_F(&myhalo[k0 + i], pp[i]);
    }
    if (jloc == SROWS - 1) {
      #pragma unroll
      for (int i = 0; i < 32; ++i) AST_F(&myhalo[256 + k0 + i], pp[i]);
    }
    drain_vm();
    __syncthreads();
    if (tid == 0)
      __hip_atomic_fetch_add(&cntP[b * NIT1 + it], 1, __ATOMIC_RELAXED,
                             __HIP_MEMORY_SCOPE_AGENT);
  }

  float* oB = out + gbase;
  #pragma unroll
  for (int i = 0; i < 32; ++i) oB[i] = uu[i];
}

extern "C" void kernel_launch(void* const* d_in, const int* in_sizes, int n_in,
                              void* d_out, int out_size, void* d_ws, size_t ws_size,
                              hipStream_t stream) {
  const float* alpha = (const float*)d_in[0];   // (64, 257, 257) fp32
  const float* frhs  = (const float*)d_in[1];   // (256, 256) fp32
  float* out = (float*)d_out;                   // (64, 256, 256) fp32

  char* ws = (char*)d_ws;
  int*   Z    = (int*)ws;                               // 5 int arrays [64][301]
  float* av   = (float*)(ws + (size_t)5 * SARR * 4);
  float* bv   = (float*)(ws + (size_t)6 * SARR * 4);
  size_t ZR   = ((size_t)7 * SARR * 4 + 4095) & ~(size_t)4095;
  float* halo  = (float*)(ws + ZR);                     // 2 MB
  float* pbuf  = (float*)(ws + ZR + (size_t)NBLK * 512 * 4);
  float* apbuf = pbuf  + (size_t)NBATCH * MM * MM;      // 16 MB each
  float* rbuf  = apbuf + (size_t)NBATCH * MM * MM;

  int nz = 5 * SARR;
  hipLaunchKernelGGL(init_ws_kernel, dim3((nz + 255) / 256), dim3(256), 0, stream,
                     Z, nz);
  hipLaunchKernelGGL(cg_kernel, dim3(NBLK), dim3(TPB), 0, stream,
                     alpha, frhs, out, Z, av, bv, halo, pbuf, apbuf, rbuf);
}